// Round 6
// baseline (309.713 us; speedup 1.0000x reference)
//
#include <hip/hip_runtime.h>

#define NN 10000
#define NE 640000
#define CH 128
#define NH 8
#define HD 16
#define BD 32
#define NEG 0.01f
#define SLOTS 160    // per-node edge-slot stride; deg ~ Poisson(64), P(>=160) ~ 1e-25
#define NCHUNK 128   // counting-sort chunks
#define CHSZ (NE / NCHUNK)   // 5000 edges per chunk

#define GEMM_BLOCKS (NN / 16)            // 625 (16 rows per block)

typedef unsigned short u16;
using frag_ab = __attribute__((ext_vector_type(8))) short;  // 8 bf16 (4 VGPRs)
using frag_cd = __attribute__((ext_vector_type(4))) float;  // 4 fp32

// bf16 round-to-nearest-even
__device__ __forceinline__ u16 bf16h(float f) {
    unsigned b = __float_as_uint(f);
    b += 0x7fffu + ((b >> 16) & 1u);
    return (u16)(b >> 16);
}
__device__ __forceinline__ float bf2f(u16 h) {
    return __uint_as_float((unsigned)h << 16);
}

// DPP butterfly sum over each 16-lane row (one head = 16 channels): pure VALU.
template <int CTRL>
__device__ __forceinline__ float dpp_add(float x) {
    int v = __builtin_amdgcn_update_dpp(0, __float_as_int(x), CTRL, 0xF, 0xF, true);
    return x + __int_as_float(v);
}
__device__ __forceinline__ float sum16(float x) {
    x = dpp_add<0xB1>(x);   // quad_perm xor1
    x = dpp_add<0x4E>(x);   // quad_perm xor2
    x = dpp_add<0x141>(x);  // row_half_mirror
    x = dpp_add<0x140>(x);  // row_mirror
    return x;
}

// ---------------- K1: histA (LDS chunk histogram) + wprep, block-range merged.
// Blocks 0..127: chunk histogram of 5000 edges into 40KB LDS, then coalesced
// dump to Ccount[chunk*NN + n]. Replaces 640k GLOBAL returning atomics (R2-R5:
// ~135us, coherent-point RMW serialization on 10k hot addrs) with LDS atomics.
// Blocks 128..175: weight prep (bf16 hi/lo split into MFMA B-fragment order:
// Wfrag[(mat*2+hilo)*16384 + (nt*4+ks)*512 + lane*8 + i],
// element (k,n): nt=n>>4, ks=k>>5, lane=((k&31)>>3)*16+(n&15), i=k&7).
__global__ __launch_bounds__(256) void histA_wprep_kernel(
    const int* __restrict__ eidx, int* __restrict__ Ccount,
    const float* __restrict__ WQ, const float* __restrict__ WK,
    const float* __restrict__ WV, u16* __restrict__ Wfrag)
{
    __shared__ int h[NN];
    if (blockIdx.x < NCHUNK) {
        int chunk = blockIdx.x;
        for (int i = threadIdx.x; i < NN; i += 256) h[i] = 0;
        __syncthreads();
        int e0 = chunk * CHSZ;
        for (int i = threadIdx.x; i < CHSZ; i += 256)
            atomicAdd(&h[eidx[NE + e0 + i]], 1);
        __syncthreads();
        int* dst = Ccount + (size_t)chunk * NN;
        for (int i = threadIdx.x; i < NN; i += 256) dst[i] = h[i];
        return;
    }
    int mat = (blockIdx.x - NCHUNK) >> 4;
    int j0 = ((blockIdx.x - NCHUNK) & 15) * 4;
    const float* W = mat == 0 ? WQ : (mat == 1 ? WK : WV);
    size_t mbase = (size_t)mat * 2 * 16384;
    int t = threadIdx.x;
    for (int j = j0; j < j0 + 4; ++j) {
        int lin = j * 256 + t;          // coalesced read
        int k = lin >> 7, n = lin & 127;
        float f = W[lin];
        u16 hh = bf16h(f);
        u16 lo = bf16h(f - bf2f(hh));
        int nt = n >> 4, ks = k >> 5, kk = k & 31;
        size_t o = (size_t)(nt * 4 + ks) * 512 + (size_t)(((kk >> 3) << 4) | (n & 15)) * 8 + (kk & 7);
        Wfrag[mbase + o] = hh;
        Wfrag[mbase + 16384 + o] = lo;
    }
}

// ---------------- K2: histB — per-node scan over chunks (in-place bases) -----
// Thread n: acc=0; for c: base=acc; acc+=Ccount[c][n]; Ccount[c][n]=base.
// counts[n]=acc. Strided-NN accesses are coalesced across threads.
__global__ __launch_bounds__(256) void histB_kernel(
    int* __restrict__ Ccount, int* __restrict__ counts)
{
    int n = blockIdx.x * 256 + threadIdx.x;
    if (n >= NN) return;
    int acc = 0;
    for (int c = 0; c < NCHUNK; ++c) {
        size_t idx = (size_t)c * NN + n;
        int v = Ccount[idx];
        Ccount[idx] = acc;
        acc += v;
    }
    counts[n] = acc;
}

// ---------------- K3: histC (LDS-cursor scatter) + MFMA gemm, merged ---------
// Blocks 0..127: chunk scatter — r = ds_add_rtn(cur[dst]) + Ccount[chunk][dst]
// gives a unique contiguous slot per (dst); write es[dst*SLOTS+r]={e,src}.
// Blocks 128..752: MFMA projections (16 node-rows/block; wave w covers column
// tiles {2w,2w+1} for Q,K,V; fp32 exactness via 3-term bf16 split
// Ah*Wh + Ah*Wl + Al*Wh). K,V bf16-packed into KVP (proven error path).
__global__ __launch_bounds__(256) void histC_gemm_kernel(
    const int* __restrict__ eidx, const int* __restrict__ Ccount,
    int2* __restrict__ es,
    const float* __restrict__ senders, const float* __restrict__ receivers,
    const u16* __restrict__ Wfrag,
    float* __restrict__ Qn, unsigned* __restrict__ KVP)
{
    __shared__ int cur[NN];
    if (blockIdx.x < NCHUNK) {
        int chunk = blockIdx.x;
        for (int i = threadIdx.x; i < NN; i += 256) cur[i] = 0;
        __syncthreads();
        int e0 = chunk * CHSZ;
        const int* base = Ccount + (size_t)chunk * NN;
        for (int i = threadIdx.x; i < CHSZ; i += 256) {
            int e = e0 + i;
            int d = eidx[NE + e];
            int s = eidx[e];
            int r = atomicAdd(&cur[d], 1) + base[d];
            es[d * SLOTS + r] = make_int2(e, s);
        }
        return;
    }

    int blk = blockIdx.x - NCHUNK;
    int wave = threadIdx.x >> 6, l = threadIdx.x & 63;
    int r0 = blk * 16;
    int arow = r0 + (l & 15);           // A-fragment row for this lane
    int kcol = (l >> 4) * 8;            // A-fragment k-offset within 32-k step

    // Load this strip's A rows (fp32) and split to bf16 hi/lo fragments.
    frag_ab Rh[4], Rl[4], Sh[4], Sl[4];
#pragma unroll
    for (int ks = 0; ks < 4; ++ks) {
        const float* rp = receivers + (size_t)arow * CH + ks * 32 + kcol;
        const float* sp = senders   + (size_t)arow * CH + ks * 32 + kcol;
        float4 ra = *(const float4*)rp, rb = *(const float4*)(rp + 4);
        float4 sa = *(const float4*)sp, sb = *(const float4*)(sp + 4);
        float rf[8] = {ra.x, ra.y, ra.z, ra.w, rb.x, rb.y, rb.z, rb.w};
        float sf[8] = {sa.x, sa.y, sa.z, sa.w, sb.x, sb.y, sb.z, sb.w};
#pragma unroll
        for (int i = 0; i < 8; ++i) {
            u16 rh = bf16h(rf[i]);  Rh[ks][i] = (short)rh;
            Rl[ks][i] = (short)bf16h(rf[i] - bf2f(rh));
            u16 sh = bf16h(sf[i]);  Sh[ks][i] = (short)sh;
            Sl[ks][i] = (short)bf16h(sf[i] - bf2f(sh));
        }
    }

    // W fragment loader: contiguous 16B per lane, fully coalesced, L2-hot.
    auto ldw = [&](int mat, int hilo, int nt, int ks) -> frag_ab {
        return *(const frag_ab*)(Wfrag + (size_t)(mat * 2 + hilo) * 16384
                                       + (size_t)(nt * 4 + ks) * 512 + l * 8);
    };

#pragma unroll
    for (int nts = 0; nts < 2; ++nts) {
        int nt = wave * 2 + nts;
        frag_cd aQ = {0.f, 0.f, 0.f, 0.f};
        frag_cd aK = {0.f, 0.f, 0.f, 0.f};
        frag_cd aV = {0.f, 0.f, 0.f, 0.f};
#pragma unroll
        for (int ks = 0; ks < 4; ++ks) {
            aQ = __builtin_amdgcn_mfma_f32_16x16x32_bf16(Rh[ks], ldw(0, 0, nt, ks), aQ, 0, 0, 0);
            aQ = __builtin_amdgcn_mfma_f32_16x16x32_bf16(Rh[ks], ldw(0, 1, nt, ks), aQ, 0, 0, 0);
            aQ = __builtin_amdgcn_mfma_f32_16x16x32_bf16(Rl[ks], ldw(0, 0, nt, ks), aQ, 0, 0, 0);
            aK = __builtin_amdgcn_mfma_f32_16x16x32_bf16(Sh[ks], ldw(1, 0, nt, ks), aK, 0, 0, 0);
            aK = __builtin_amdgcn_mfma_f32_16x16x32_bf16(Sh[ks], ldw(1, 1, nt, ks), aK, 0, 0, 0);
            aK = __builtin_amdgcn_mfma_f32_16x16x32_bf16(Sl[ks], ldw(1, 0, nt, ks), aK, 0, 0, 0);
            aV = __builtin_amdgcn_mfma_f32_16x16x32_bf16(Sh[ks], ldw(2, 0, nt, ks), aV, 0, 0, 0);
            aV = __builtin_amdgcn_mfma_f32_16x16x32_bf16(Sh[ks], ldw(2, 1, nt, ks), aV, 0, 0, 0);
            aV = __builtin_amdgcn_mfma_f32_16x16x32_bf16(Sl[ks], ldw(2, 0, nt, ks), aV, 0, 0, 0);
        }
        // D layout: col = lane&15, row = (lane>>4)*4 + j  [guide §3, m89-verified]
#pragma unroll
        for (int j = 0; j < 4; ++j) {
            int orow = r0 + (l >> 4) * 4 + j;
            int ocol = nt * 16 + (l & 15);
            size_t o = (size_t)orow * CH + ocol;
            Qn[o] = aQ[j];
            KVP[o] = (unsigned)bf16h(aK[j]) | ((unsigned)bf16h(aV[j]) << 16);
        }
    }
}

// ---------------- fused per-node edge loop (UNCHANGED except counts[n]) ------
// One WAVE per node, lane l owns channels l and l+64. 8-edge tiles; eattr
// rows via wave-uniform s_load. KV gather: ONE dword per (edge, lane, half).
// Do not reshape this loop (R8/R9/R11 prev-session regressions; R1 edge-split
// regression; R4 (256,8) VGPR-32 spill; R3/R5 occupancy levers: NO effect —
// don't retry occupancy, idle is shared-path latency).
__global__ __launch_bounds__(128) void fused_kernel(
    const int2* __restrict__ es, const int* __restrict__ counts,
    const float* __restrict__ eattr, const float* __restrict__ WE,
    const float* __restrict__ att, const float* __restrict__ Qn,
    const unsigned* __restrict__ KVP, float* __restrict__ out)
{
    int wave = threadIdx.x >> 6, l = threadIdx.x & 63;
    int n = blockIdx.x * 2 + wave;            // 5000 blocks * 2 waves = NN
    int start = n * SLOTS;
    int end = start + counts[n];

    float rWE[2 * BD];
#pragma unroll
    for (int k = 0; k < BD; ++k) {
        rWE[k]      = WE[k * CH + l];
        rWE[BD + k] = WE[k * CH + 64 + l];
    }
#pragma unroll
    for (int k = 0; k < 2 * BD; ++k) asm volatile("" : "+v"(rWE[k]));

    float a0 = att[l], a1 = att[64 + l];
    float q0 = Qn[(size_t)n * CH + l], q1 = Qn[(size_t)n * CH + 64 + l];
    float acc0 = 0.f, acc1 = 0.f, sum0 = 0.f, sum1 = 0.f;

    for (int base = start; base < end; base += 8) {
        int m = end - base;                   // >=1
        int idx = base + (l & 7);
        if (idx >= end) idx = end - 1;
        int2 esv = es[idx];
#pragma unroll 8
        for (int t = 0; t < 8; ++t) {
            if (t >= m) break;                // wave-uniform
            int e   = __builtin_amdgcn_readlane(esv.x, t);
            int src = __builtin_amdgcn_readlane(esv.y, t);
            const float* __restrict__ row = eattr + (size_t)e * BD;
            size_t so = (size_t)src * CH;
            unsigned p0 = KVP[so + l];
            unsigned p1 = KVP[so + 64 + l];
            float kb0 = __uint_as_float(p0 << 16);
            float kb1 = __uint_as_float(p1 << 16);
            float vv0 = __uint_as_float(p0 & 0xffff0000u);
            float vv1 = __uint_as_float(p1 & 0xffff0000u);
            float ec0 = 0.f, ec1 = 0.f;
#pragma unroll
            for (int k = 0; k < BD; ++k) {
                float rv = row[k];            // uniform -> s_load
                ec0 = fmaf(rv, rWE[k],      ec0);
                ec1 = fmaf(rv, rWE[BD + k], ec1);
            }
            float h0 = q0 + kb0 + ec0; h0 = h0 > 0.f ? h0 : NEG * h0;
            float h1 = q1 + kb1 + ec1; h1 = h1 > 0.f ? h1 : NEG * h1;
            float t0 = sum16(a0 * h0);
            float t1 = sum16(a1 * h1);
            float e0 = __expf(t0), e1 = __expf(t1);
            sum0 += e0; acc0 = fmaf(e0, vv0, acc0);
            sum1 += e1; acc1 = fmaf(e1, vv1, acc1);
        }
    }
    out[(size_t)n * CH + l]      = (end > start) ? acc0 / sum0 : 0.f;
    out[(size_t)n * CH + 64 + l] = (end > start) ? acc1 / sum1 : 0.f;
}

extern "C" void kernel_launch(void* const* d_in, const int* in_sizes, int n_in,
                              void* d_out, int out_size, void* d_ws, size_t ws_size,
                              hipStream_t stream)
{
    const float* senders   = (const float*)d_in[0];
    const float* receivers = (const float*)d_in[1];
    const int*   eidx      = (const int*)d_in[2];
    const float* eattr     = (const float*)d_in[3];
    const float* WQ  = (const float*)d_in[4];
    const float* WK  = (const float*)d_in[5];
    const float* WV  = (const float*)d_in[6];
    const float* WE  = (const float*)d_in[7];
    const float* att = (const float*)d_in[8];
    float* out = (float*)d_out;

    char* ws = (char*)d_ws;
    size_t off = 0;
    auto alloc = [&](size_t bytes) -> void* {
        void* p = ws + off;
        off += (bytes + 255) & ~(size_t)255;
        return p;
    };
    // Qn 5.12 + KVP 5.12 + counts 0.04 + es 12.8 + Wfrag 0.20 + Ccount 5.12
    // = 28.4 MB (< 38.5 MB proven safe; 43.7 MB failed)
    float*    Qn     = (float*)alloc((size_t)NN * CH * 4);
    unsigned* KVP    = (unsigned*)alloc((size_t)NN * CH * 4);
    int*      counts = (int*)alloc((size_t)NN * 4);
    int2*     es     = (int2*)alloc((size_t)NN * SLOTS * 8);
    u16*      Wfrag  = (u16*)alloc((size_t)3 * 2 * 16384 * 2);
    int*      Ccount = (int*)alloc((size_t)NCHUNK * NN * 4);

    // No memset needed: histB writes every counts[n]; LDS cursors zeroed in-block.
    histA_wprep_kernel<<<NCHUNK + 48, 256, 0, stream>>>(
        eidx, Ccount, WQ, WK, WV, Wfrag);
    histB_kernel<<<(NN + 255) / 256, 256, 0, stream>>>(Ccount, counts);
    histC_gemm_kernel<<<NCHUNK + GEMM_BLOCKS, 256, 0, stream>>>(
        eidx, Ccount, es, senders, receivers, Wfrag, Qn, KVP);
    fused_kernel<<<NN / 2, 128, 0, stream>>>(es, counts, eattr, WE, att, Qn, KVP, out);
}

// Round 7
// 308.095 us; speedup vs baseline: 1.0053x; 1.0053x over previous
//
#include <hip/hip_runtime.h>
#include <hip/hip_fp16.h>

#define NN 10000
#define NE 640000
#define CH 128
#define NH 8
#define HD 16
#define BD 32
#define NEG 0.01f
#define SLOTS 160    // per-node edge-slot stride; max deg ~100 observed
#define NCHUNK 64    // counting-sort chunks
#define CHSZ (NE / NCHUNK)   // 10000 edges per chunk

#define HISTB_BLOCKS 40
#define GEMM_BLOCKS (NN / 16)      // 625
#define EDGE_BLOCKS (NE / 64)      // 10000 (64 edges per 256-thr block)

typedef unsigned short u16;
using frag_ab = __attribute__((ext_vector_type(8))) short;  // 8 bf16 (4 VGPRs)
using frag_cd = __attribute__((ext_vector_type(4))) float;  // 4 fp32

// bf16 round-to-nearest-even
__device__ __forceinline__ u16 bf16h(float f) {
    unsigned b = __float_as_uint(f);
    b += 0x7fffu + ((b >> 16) & 1u);
    return (u16)(b >> 16);
}
__device__ __forceinline__ float bf2f(u16 h) {
    return __uint_as_float((unsigned)h << 16);
}

// DPP butterfly sum over each 16-lane row: pure VALU.
template <int CTRL>
__device__ __forceinline__ float dpp_add(float x) {
    int v = __builtin_amdgcn_update_dpp(0, __float_as_int(x), CTRL, 0xF, 0xF, true);
    return x + __int_as_float(v);
}
__device__ __forceinline__ float sum16(float x) {
    x = dpp_add<0xB1>(x);   // quad_perm xor1
    x = dpp_add<0x4E>(x);   // quad_perm xor2
    x = dpp_add<0x141>(x);  // row_half_mirror
    x = dpp_add<0x140>(x);  // row_mirror
    return x;
}

// ---------------- K1: histA (LDS chunk histogram) + weight prep --------------
// Blocks 0..63: chunk histogram (10000 edges) into 40KB LDS, coalesced dump to
// Ccount[chunk*NN+n]. Blocks 64..111: WQ/WK/WV bf16 hi/lo split into MFMA
// B-frag order (Wfrag[(mat*2+hilo)*16384 + (nt*4+ks)*512 + lane*8 + i], element
// (k,n): nt=n>>4, ks=k>>5, lane=((k&31)>>3)*16+(n&15), i=k&7). Block 112: same
// for WE (32x128, ks=0 only): WEfrag[hilo*4096 + nt*512 + lane*8 + i].
__global__ __launch_bounds__(256) void histA_wprep_kernel(
    const int* __restrict__ eidx, int* __restrict__ Ccount,
    const float* __restrict__ WQ, const float* __restrict__ WK,
    const float* __restrict__ WV, const float* __restrict__ WE,
    u16* __restrict__ Wfrag, u16* __restrict__ WEfrag)
{
    __shared__ int h[NN];
    if (blockIdx.x < NCHUNK) {
        int chunk = blockIdx.x;
        for (int i = threadIdx.x; i < NN; i += 256) h[i] = 0;
        __syncthreads();
        int e0 = chunk * CHSZ;
        for (int i = threadIdx.x; i < CHSZ; i += 256)
            atomicAdd(&h[eidx[NE + e0 + i]], 1);
        __syncthreads();
        int* dst = Ccount + (size_t)chunk * NN;
        for (int i = threadIdx.x; i < NN; i += 256) dst[i] = h[i];
        return;
    }
    int b = blockIdx.x - NCHUNK;
    int t = threadIdx.x;
    if (b < 48) {
        int mat = b >> 4;
        int j0 = (b & 15) * 4;
        const float* W = mat == 0 ? WQ : (mat == 1 ? WK : WV);
        size_t mbase = (size_t)mat * 2 * 16384;
        for (int j = j0; j < j0 + 4; ++j) {
            int lin = j * 256 + t;
            int k = lin >> 7, n = lin & 127;
            float f = W[lin];
            u16 hh = bf16h(f);
            u16 lo = bf16h(f - bf2f(hh));
            int nt = n >> 4, ks = k >> 5, kk = k & 31;
            size_t o = (size_t)(nt * 4 + ks) * 512 + (size_t)(((kk >> 3) << 4) | (n & 15)) * 8 + (kk & 7);
            Wfrag[mbase + o] = hh;
            Wfrag[mbase + 16384 + o] = lo;
        }
    } else {
        // WE prep: 32*128 = 4096 elements
        for (int j = 0; j < 16; ++j) {
            int lin = j * 256 + t;
            int k = lin >> 7, n = lin & 127;
            float f = WE[lin];
            u16 hh = bf16h(f);
            u16 lo = bf16h(f - bf2f(hh));
            int nt = n >> 4;
            size_t o = (size_t)nt * 512 + (size_t)(((k >> 3) << 4) | (n & 15)) * 8 + (k & 7);
            WEfrag[o] = hh;
            WEfrag[4096 + o] = lo;
        }
    }
}

// ---------------- K2: histB scan + MFMA projections (merged) -----------------
// Blocks 0..39: per-node chunk scan (in-place bases) + counts.
// Blocks 40..664: proj GEMM. Wave w covers column tiles nt={w, w+4} so each
// lane holds both c and c+64 -> pack K,V as bf16 pairs {x[c],x[c+64]}:
// KP/VP[n*64 + c] (c<64). Q stays fp32. 3-term split Ah*Wh+Ah*Wl+Al*Wh.
__global__ __launch_bounds__(256) void histB_proj_kernel(
    int* __restrict__ Ccount, int* __restrict__ counts,
    const float* __restrict__ senders, const float* __restrict__ receivers,
    const u16* __restrict__ Wfrag,
    float* __restrict__ Qn, unsigned* __restrict__ KP, unsigned* __restrict__ VP)
{
    if (blockIdx.x < HISTB_BLOCKS) {
        int n = blockIdx.x * 256 + threadIdx.x;
        if (n >= NN) return;
        int acc = 0;
        for (int c = 0; c < NCHUNK; ++c) {
            size_t idx = (size_t)c * NN + n;
            int v = Ccount[idx];
            Ccount[idx] = acc;
            acc += v;
        }
        counts[n] = acc;
        return;
    }

    int blk = blockIdx.x - HISTB_BLOCKS;
    int wave = threadIdx.x >> 6, l = threadIdx.x & 63;
    int r0 = blk * 16;
    int arow = r0 + (l & 15);
    int kcol = (l >> 4) * 8;

    frag_ab Rh[4], Rl[4], Sh[4], Sl[4];
#pragma unroll
    for (int ks = 0; ks < 4; ++ks) {
        const float* rp = receivers + (size_t)arow * CH + ks * 32 + kcol;
        const float* sp = senders   + (size_t)arow * CH + ks * 32 + kcol;
        float4 ra = *(const float4*)rp, rb = *(const float4*)(rp + 4);
        float4 sa = *(const float4*)sp, sb = *(const float4*)(sp + 4);
        float rf[8] = {ra.x, ra.y, ra.z, ra.w, rb.x, rb.y, rb.z, rb.w};
        float sf[8] = {sa.x, sa.y, sa.z, sa.w, sb.x, sb.y, sb.z, sb.w};
#pragma unroll
        for (int i = 0; i < 8; ++i) {
            u16 rh = bf16h(rf[i]);  Rh[ks][i] = (short)rh;
            Rl[ks][i] = (short)bf16h(rf[i] - bf2f(rh));
            u16 sh = bf16h(sf[i]);  Sh[ks][i] = (short)sh;
            Sl[ks][i] = (short)bf16h(sf[i] - bf2f(sh));
        }
    }

    auto ldw = [&](int mat, int hilo, int nt, int ks) -> frag_ab {
        return *(const frag_ab*)(Wfrag + (size_t)(mat * 2 + hilo) * 16384
                                       + (size_t)(nt * 4 + ks) * 512 + l * 8);
    };

    frag_cd aQ[2], aK[2], aV[2];
#pragma unroll
    for (int s = 0; s < 2; ++s) {
        int nt = wave + s * 4;
        aQ[s] = frag_cd{0.f, 0.f, 0.f, 0.f};
        aK[s] = frag_cd{0.f, 0.f, 0.f, 0.f};
        aV[s] = frag_cd{0.f, 0.f, 0.f, 0.f};
#pragma unroll
        for (int ks = 0; ks < 4; ++ks) {
            aQ[s] = __builtin_amdgcn_mfma_f32_16x16x32_bf16(Rh[ks], ldw(0, 0, nt, ks), aQ[s], 0, 0, 0);
            aQ[s] = __builtin_amdgcn_mfma_f32_16x16x32_bf16(Rh[ks], ldw(0, 1, nt, ks), aQ[s], 0, 0, 0);
            aQ[s] = __builtin_amdgcn_mfma_f32_16x16x32_bf16(Rl[ks], ldw(0, 0, nt, ks), aQ[s], 0, 0, 0);
            aK[s] = __builtin_amdgcn_mfma_f32_16x16x32_bf16(Sh[ks], ldw(1, 0, nt, ks), aK[s], 0, 0, 0);
            aK[s] = __builtin_amdgcn_mfma_f32_16x16x32_bf16(Sh[ks], ldw(1, 1, nt, ks), aK[s], 0, 0, 0);
            aK[s] = __builtin_amdgcn_mfma_f32_16x16x32_bf16(Sl[ks], ldw(1, 0, nt, ks), aK[s], 0, 0, 0);
            aV[s] = __builtin_amdgcn_mfma_f32_16x16x32_bf16(Sh[ks], ldw(2, 0, nt, ks), aV[s], 0, 0, 0);
            aV[s] = __builtin_amdgcn_mfma_f32_16x16x32_bf16(Sh[ks], ldw(2, 1, nt, ks), aV[s], 0, 0, 0);
            aV[s] = __builtin_amdgcn_mfma_f32_16x16x32_bf16(Sl[ks], ldw(2, 0, nt, ks), aV[s], 0, 0, 0);
        }
    }
    // D layout: col = lane&15, row = (lane>>4)*4 + j
#pragma unroll
    for (int j = 0; j < 4; ++j) {
        int orow = r0 + (l >> 4) * 4 + j;
        int c = wave * 16 + (l & 15);          // c in [0,64)
        Qn[(size_t)orow * CH + c]      = aQ[0][j];
        Qn[(size_t)orow * CH + c + 64] = aQ[1][j];
        KP[(size_t)orow * 64 + c] = (unsigned)bf16h(aK[0][j]) | ((unsigned)bf16h(aK[1][j]) << 16);
        VP[(size_t)orow * 64 + c] = (unsigned)bf16h(aV[0][j]) | ((unsigned)bf16h(aV[1][j]) << 16);
    }
}

// ---------------- K3: histC scatter + MFMA edge-logit pass (merged) ----------
// Blocks 0..63: chunk scatter via LDS cursors + bases -> es[dst*SLOTS+r]={e,src}.
// Blocks 64..10063: 16 edges/wave tile. E = eattr@WE via 3 MFMAs per col-tile
// (24 total); head h == col-tile nt, so logit[r,h] = sum16(att_c * leakyrelu(
// Q[dst,c]+K[src,c]+E[r,c])) straight from the D-layout. ex stored fp16 pairs
// exP[e*4+g] = {ex[g], ex[g+4]} (fp16 ex proven R1; bf16 K + split-E proven).
__global__ __launch_bounds__(256) void histC_edge_kernel(
    const int* __restrict__ eidx, const int* __restrict__ Ccount,
    int2* __restrict__ es,
    const float* __restrict__ eattr, const u16* __restrict__ WEfrag,
    const float* __restrict__ att, const float* __restrict__ Qn,
    const unsigned* __restrict__ KP, unsigned* __restrict__ exP)
{
    __shared__ int cur[NN];
    if (blockIdx.x < NCHUNK) {
        int chunk = blockIdx.x;
        for (int i = threadIdx.x; i < NN; i += 256) cur[i] = 0;
        __syncthreads();
        int e0 = chunk * CHSZ;
        const int* base = Ccount + (size_t)chunk * NN;
        for (int i = threadIdx.x; i < CHSZ; i += 256) {
            int e = e0 + i;
            int d = eidx[NE + e];
            int s = eidx[e];
            int r = atomicAdd(&cur[d], 1) + base[d];
            es[d * SLOTS + r] = make_int2(e, s);
        }
        return;
    }

    int blk = blockIdx.x - NCHUNK;
    int wave = threadIdx.x >> 6, l = threadIdx.x & 63;
    int e0 = (blk * 4 + wave) * 16;          // 16-edge tile

    // A fragment: row = l&15 (edge), k = 8*(l>>4)+i; split hi/lo
    const float* ap = eattr + (size_t)(e0 + (l & 15)) * BD + (l >> 4) * 8;
    float4 a0 = *(const float4*)ap, a1 = *(const float4*)(ap + 4);
    float af[8] = {a0.x, a0.y, a0.z, a0.w, a1.x, a1.y, a1.z, a1.w};
    frag_ab Ah, Al;
#pragma unroll
    for (int i = 0; i < 8; ++i) {
        u16 hh = bf16h(af[i]);
        Ah[i] = (short)hh;
        Al[i] = (short)bf16h(af[i] - bf2f(hh));
    }

    frag_cd acc[8];
#pragma unroll
    for (int nt = 0; nt < 8; ++nt) {
        frag_ab Bh = *(const frag_ab*)(WEfrag + (size_t)nt * 512 + l * 8);
        frag_ab Bl = *(const frag_ab*)(WEfrag + 4096 + (size_t)nt * 512 + l * 8);
        frag_cd a = frag_cd{0.f, 0.f, 0.f, 0.f};
        a = __builtin_amdgcn_mfma_f32_16x16x32_bf16(Ah, Bh, a, 0, 0, 0);
        a = __builtin_amdgcn_mfma_f32_16x16x32_bf16(Ah, Bl, a, 0, 0, 0);
        a = __builtin_amdgcn_mfma_f32_16x16x32_bf16(Al, Bh, a, 0, 0, 0);
        acc[nt] = a;
    }

    // att coefficients for this lane's column within each head tile
    float attc[8];
#pragma unroll
    for (int nt = 0; nt < 8; ++nt) attc[nt] = att[nt * 16 + (l & 15)];

    // rows owned by this lane: r = (l>>4)*4 + j  ->  edge e0 + r
#pragma unroll
    for (int j = 0; j < 4; ++j) {
        int ej = e0 + (l >> 4) * 4 + j;
        int dst = eidx[NE + ej];             // 16-lane broadcast load
        int src = eidx[ej];
        const float* qrow = Qn + (size_t)dst * CH + (l & 15);
        float q[8];
#pragma unroll
        for (int nt = 0; nt < 8; ++nt) q[nt] = qrow[nt * 16];
        unsigned kp[4];
#pragma unroll
        for (int g = 0; g < 4; ++g) kp[g] = KP[(size_t)src * 64 + g * 16 + (l & 15)];
        float ex[8];
#pragma unroll
        for (int nt = 0; nt < 8; ++nt) {
            unsigned kbits = (nt < 4) ? (kp[nt] << 16) : (kp[nt - 4] & 0xffff0000u);
            float h = q[nt] + __uint_as_float(kbits) + acc[nt][j];
            h = h > 0.f ? h : NEG * h;
            float s = sum16(attc[nt] * h);
            ex[nt] = __expf(s);
        }
        if ((l & 15) < 4) {
            int g = l & 15;
            unsigned pk = (unsigned)__half_as_ushort(__float2half(ex[g]))
                        | ((unsigned)__half_as_ushort(__float2half(ex[g + 4])) << 16);
            exP[(size_t)ej * 4 + g] = pk;
        }
    }
}

// ---------------- K4: node pass — pure weighted V gather ---------------------
// One wave per node, lane l owns channels l and l+64 (head g=l>>4 and g+4).
// Per edge: readlane {e,src}, 1 exP dword (16-lane broadcast), 1 VP dword,
// ~12 VALU. No eattr, no WE, no sum16, no exp — logits precomputed in K3.
__global__ __launch_bounds__(128) void node_kernel(
    const int2* __restrict__ es, const int* __restrict__ counts,
    const unsigned* __restrict__ exP, const unsigned* __restrict__ VP,
    float* __restrict__ out)
{
    int wave = threadIdx.x >> 6, l = threadIdx.x & 63;
    int n = blockIdx.x * 2 + wave;
    int start = n * SLOTS;
    int end = start + counts[n];
    int g = l >> 4;

    float acc0 = 0.f, acc1 = 0.f, sum0 = 0.f, sum1 = 0.f;
    for (int base = start; base < end; base += 8) {
        int m = end - base;
        int idx = base + (l & 7);
        if (idx >= end) idx = end - 1;
        int2 esv = es[idx];
#pragma unroll 8
        for (int t = 0; t < 8; ++t) {
            if (t >= m) break;               // wave-uniform
            int e   = __builtin_amdgcn_readlane(esv.x, t);
            int src = __builtin_amdgcn_readlane(esv.y, t);
            unsigned pk = exP[(size_t)e * 4 + g];
            unsigned vp = VP[(size_t)src * 64 + l];
            float ex0 = __half2float(__ushort_as_half((unsigned short)(pk & 0xffffu)));
            float ex1 = __half2float(__ushort_as_half((unsigned short)(pk >> 16)));
            float vv0 = __uint_as_float(vp << 16);
            float vv1 = __uint_as_float(vp & 0xffff0000u);
            sum0 += ex0; acc0 = fmaf(ex0, vv0, acc0);
            sum1 += ex1; acc1 = fmaf(ex1, vv1, acc1);
        }
    }
    out[(size_t)n * CH + l]      = (end > start) ? acc0 / sum0 : 0.f;
    out[(size_t)n * CH + 64 + l] = (end > start) ? acc1 / sum1 : 0.f;
}

extern "C" void kernel_launch(void* const* d_in, const int* in_sizes, int n_in,
                              void* d_out, int out_size, void* d_ws, size_t ws_size,
                              hipStream_t stream)
{
    const float* senders   = (const float*)d_in[0];
    const float* receivers = (const float*)d_in[1];
    const int*   eidx      = (const int*)d_in[2];
    const float* eattr     = (const float*)d_in[3];
    const float* WQ  = (const float*)d_in[4];
    const float* WK  = (const float*)d_in[5];
    const float* WV  = (const float*)d_in[6];
    const float* WE  = (const float*)d_in[7];
    const float* att = (const float*)d_in[8];
    float* out = (float*)d_out;

    char* ws = (char*)d_ws;
    size_t off = 0;
    auto alloc = [&](size_t bytes) -> void* {
        void* p = ws + off;
        off += (bytes + 255) & ~(size_t)255;
        return p;
    };
    // Qn 5.12 + KP 2.56 + VP 2.56 + counts 0.04 + es 12.8 + Wfrag 0.20
    // + WEfrag 0.016 + Ccount 2.56 + exP 10.24 = 36.1 MB (< 38.5 proven safe)
    float*    Qn     = (float*)alloc((size_t)NN * CH * 4);
    unsigned* KP     = (unsigned*)alloc((size_t)NN * 64 * 4);
    unsigned* VP     = (unsigned*)alloc((size_t)NN * 64 * 4);
    int*      counts = (int*)alloc((size_t)NN * 4);
    int2*     es     = (int2*)alloc((size_t)NN * SLOTS * 8);
    u16*      Wfrag  = (u16*)alloc((size_t)3 * 2 * 16384 * 2);
    u16*      WEfrag = (u16*)alloc((size_t)2 * 4096 * 2);
    int*      Ccount = (int*)alloc((size_t)NCHUNK * NN * 4);
    unsigned* exP    = (unsigned*)alloc((size_t)NE * 4 * 4);

    histA_wprep_kernel<<<NCHUNK + 49, 256, 0, stream>>>(
        eidx, Ccount, WQ, WK, WV, WE, Wfrag, WEfrag);
    histB_proj_kernel<<<HISTB_BLOCKS + GEMM_BLOCKS, 256, 0, stream>>>(
        Ccount, counts, senders, receivers, Wfrag, Qn, KP, VP);
    histC_edge_kernel<<<NCHUNK + EDGE_BLOCKS, 256, 0, stream>>>(
        eidx, Ccount, es, eattr, WEfrag, att, Qn, KP, exP);
    node_kernel<<<NN / 2, 128, 0, stream>>>(es, counts, exP, VP, out);
}